// Round 5
// baseline (102.568 us; speedup 1.0000x reference)
//
#include <hip/hip_runtime.h>

// Chamfer distance, B=16, N=M=4096, 2-D fp32 points, prefix-length masks.
// d_out: [fwd 16*4096][bwd 16*4096] fp32.
//
// R11 = R10 VERBATIM + a second (idempotent) launch of chamfer_main.
// MEASUREMENT ROUND. Rationale:
//  - R9 (45% work cut) was null; R10 (latency-tolerant reduce) gained only
//    1.8us. Accounting vs R7's directly-measured anchors leaves main+reduce
//    ~= 31us while issue-rate models say ~8us. Same 5x model-vs-measured gap
//    showed in R7's counters (46.6us, VALUBusy 11.5%, FETCH 268KB: idle,
//    not saturated). Our kernels never reach top-5 (all slots are 41us
//    fills), so total dur_us is the only instrument.
//  - chamfer_main is a pure function of its inputs (deterministic writes to
//    private slices) -> launching it twice is semantically a no-op.
//    Delta(R11-R10) = duration(main) + one launch gap.
//  - Pre-committed read: Delta>=22us -> main-internal mystery is real, R12
//    rebuilds main's scan. Delta<=12us -> dispatch overhead dominates, R12
//    goes single-dispatch (atomicMin of sqrt'd mins + sentinel init; min
//    commutes with sqrt, nonneg-float bit pattern is uint-monotone).
//    In between -> mixed.

#define NQ 16
typedef float f2 __attribute__((ext_vector_type(2)));

template<int KA>
__device__ __forceinline__ void scan_queries(
    const float* __restrict__ Qrow,          // row base of query cloud
    const float4* __restrict__ sxy, const f2* __restrict__ sn,
    float* __restrict__ slice, int tid)
{
    // KA*64 queries per wave; 4 state VGPRs per query (KA=16 -> ~90 total).
    float mx[KA], my[KA], s2[KA], best[KA];
    #pragma unroll
    for (int k = 0; k < KA; ++k) {
        const float2 q = ((const float2*)Qrow)[tid + k * 256];
        mx[k] = -2.f * q.x;
        my[k] = -2.f * q.y;
        s2[k] = fmaf(q.x, q.x, q.y * q.y);
        best[k] = 3.0e38f;
    }

    // Per point-pair per query: 2 v_pk_fma_f32 (scalar op_sel broadcast)
    // + 1 v_min3_f32; 2 broadcast LDS reads amortized over KA queries.
    #pragma unroll 4
    for (int j = 0; j < 64; ++j) {
        const float4 xy = sxy[j];
        const f2 xp = f2{xy.x, xy.y};
        const f2 yp = f2{xy.z, xy.w};
        const f2 np = sn[j];
        #pragma unroll
        for (int k = 0; k < KA; ++k) {
            f2 v = xp * mx[k] + np;       // pk_fma: n - 2qx*tx
            v = yp * my[k] + v;           // pk_fma: n - 2q.t
            best[k] = fminf(best[k], fminf(v.x, v.y));  // v_min3_f32
        }
    }

    // Plain coalesced stores to this unit's private slice. No atomics.
    #pragma unroll
    for (int k = 0; k < KA; ++k)
        slice[tid + k * 256] = fmaxf(best[k] + s2[k], 0.f);  // clamp commutes with min
}

__global__ __launch_bounds__(256, 2) void chamfer_main(
    const float* __restrict__ src, const float* __restrict__ tgt,
    const int* __restrict__ slen, const int* __restrict__ tlen,
    float* __restrict__ part)   // [32 rows][32 slices][4096] partial mins
{
    __shared__ float4 sh_xy[64];   // {x0,x1,y0,y1} per point-pair
    __shared__ f2     sh_n[64];    // {|t0|^2, |t1|^2}

    const int g   = blockIdx.x;
    const int tid = threadIdx.x;

    // Compacted work lookup: g -> (row, pc). Uniform SALU.
    int row = -1, pc = 0, Lp = 0, acc = 0;
    #pragma unroll
    for (int rr = 0; rr < 32; ++rr) {
        const int L = (rr < 16) ? tlen[rr] : slen[rr - 16];  // search-side length
        const int n = (L + 127) >> 7;                        // active 128-pt chunks
        if (row < 0 && g < acc + n) { row = rr; pc = g - acc; Lp = L; }
        acc += n;
    }
    if (row < 0) return;             // beyond total active units
    const int dir = row >> 4, b = row & 15;

    // Query-side length -> active k-slices (block-uniform).
    const int Lq = dir ? tlen[b] : slen[b];
    const int KACT = (Lq + 255) >> 8;          // 0..16
    if (KACT == 0) return;                     // uniform: no valid queries

    const float* Q = dir ? tgt : src;
    const float* P = dir ? src : tgt;

    // Stage 128 points (64 pairs), pair-packed; poison n for idx >= Lp.
    if (tid < 64) {
        const int base = pc * 128 + tid * 2;
        const float4 pp = ((const float4*)P)[(b * 4096 + base) >> 1];  // {x0,y0,x1,y1}
        const float n0 = (base + 0 < Lp) ? fmaf(pp.x, pp.x, pp.y * pp.y) : 1e30f;
        const float n1 = (base + 1 < Lp) ? fmaf(pp.z, pp.z, pp.w * pp.w) : 1e30f;
        sh_xy[tid] = make_float4(pp.x, pp.z, pp.y, pp.w);    // {x0,x1,y0,y1}
        sh_n[tid]  = f2{n0, n1};
    }
    __syncthreads();

    const float* Qrow = Q + b * 8192;                       // row base (float2 elems)
    float* slice = part + ((size_t)row * 32 + pc) * 4096;

    // Uniform dispatch on rounded-up active query slices. Queries in
    // [Lq, KA*256) are computed wastefully but masked by the reduce.
    switch ((KACT + 3) >> 2) {
        case 1:  scan_queries< 4>(Qrow, sh_xy, sh_n, slice, tid); break;
        case 2:  scan_queries< 8>(Qrow, sh_xy, sh_n, slice, tid); break;
        case 3:  scan_queries<12>(Qrow, sh_xy, sh_n, slice, tid); break;
        default: scan_queries<16>(Qrow, sh_xy, sh_n, slice, tid); break;
    }
}

__global__ __launch_bounds__(256) void chamfer_reduce(
    const float* __restrict__ part,
    const int* __restrict__ slen, const int* __restrict__ tlen,
    float* __restrict__ out)
{
    __shared__ float4 sh[4][64];                 // per-wave partial float4 mins

    const int blk = blockIdx.x;                  // 512 = 32 rows x 16 segments
    const int row = blk >> 4, seg = blk & 15;
    const int dir = row >> 4, b = row & 15;
    const int tid = threadIdx.x;
    const int f4  = tid & 63;                    // float4 index within segment
    const int w   = tid >> 6;                    // wave id = slice quarter

    const int Lq = dir ? tlen[b] : slen[b];
    const int Lp = dir ? slen[b] : tlen[b];

    float4* out4 = (float4*)(out + row * 4096 + seg * 256);

    if (seg * 256 >= Lq) {                       // whole segment padded -> zeros
        if (w == 0) out4[f4] = make_float4(0.f, 0.f, 0.f, 0.f);
        return;
    }

    // Loads below only touch i < ceil(Lq/256)*256 <= KA*256: always written
    // by main under query-skip (never reads ws poison).
    const int nact = (Lp + 127) >> 7;            // 0..32 active slices
    const int nw = min(max(nact - w * 8, 0), 8); // this wave's slice count (uniform)

    const int i = seg * 256 + f4 * 4;            // first float of this float4
    float4 best = make_float4(1e10f, 1e10f, 1e10f, 1e10f);
    const float4* p = (const float4*)(part + ((size_t)row * 32 + w * 8) * 4096 + i);
    #pragma unroll
    for (int j = 0; j < 8; ++j) {                // compile-time unrolled: all
        if (j < nw) {                            // loads issued before waits
            const float4 v = p[(size_t)j * 1024];
            best.x = fminf(best.x, v.x);
            best.y = fminf(best.y, v.y);
            best.z = fminf(best.z, v.z);
            best.w = fminf(best.w, v.w);
        }
    }
    sh[w][f4] = best;
    __syncthreads();

    if (tid < 64) {
        const float4 a = sh[0][tid], c = sh[1][tid], d = sh[2][tid], e = sh[3][tid];
        float4 m;
        m.x = fminf(fminf(a.x, c.x), fminf(d.x, e.x));
        m.y = fminf(fminf(a.y, c.y), fminf(d.y, e.y));
        m.z = fminf(fminf(a.z, c.z), fminf(d.z, e.z));
        m.w = fminf(fminf(a.w, c.w), fminf(d.w, e.w));
        const int ii = seg * 256 + tid * 4;
        float4 r;                                // nact==0 -> sqrt(1e10), matches ref
        r.x = (ii + 0 < Lq) ? sqrtf(fmaxf(m.x, 0.f)) : 0.f;
        r.y = (ii + 1 < Lq) ? sqrtf(fmaxf(m.y, 0.f)) : 0.f;
        r.z = (ii + 2 < Lq) ? sqrtf(fmaxf(m.z, 0.f)) : 0.f;
        r.w = (ii + 3 < Lq) ? sqrtf(fmaxf(m.w, 0.f)) : 0.f;
        out4[tid] = r;
    }
}

extern "C" void kernel_launch(void* const* d_in, const int* in_sizes, int n_in,
                              void* d_out, int out_size, void* d_ws, size_t ws_size,
                              hipStream_t stream) {
    const float* src = (const float*)d_in[0];   // [16,4096,2] f32
    const float* tgt = (const float*)d_in[1];   // [16,4096,2] f32
    const int* slen  = (const int*)d_in[2];     // [16] i32
    const int* tlen  = (const int*)d_in[3];     // [16] i32
    float* part = (float*)d_ws;                 // 32 x 32 x 4096 f32 = 16.8 MB

    // MEASUREMENT: main launched twice (idempotent). Delta vs R10's 82.9us
    // = duration(main) + one launch gap. See header for pre-committed read.
    chamfer_main<<<1024, 256, 0, stream>>>(src, tgt, slen, tlen, part);
    chamfer_main<<<1024, 256, 0, stream>>>(src, tgt, slen, tlen, part);
    chamfer_reduce<<<512, 256, 0, stream>>>(part, slen, tlen, (float*)d_out);
}

// Round 8
// 79.277 us; speedup vs baseline: 1.2938x; 1.2938x over previous
//
#include <hip/hip_runtime.h>

// Chamfer distance, B=16, N=M=4096, 2-D fp32 points, prefix-length masks.
// d_out: [fwd 16*4096][bwd 16*4096] fp32.
//
// R14 = R13 with the init-memset size bug fixed.
//  - R12/R13 post-mortem: BIT-IDENTICAL deterministic failure (1.468750)
//    across two structurally different kernels -> not a race. Harness
//    traceback shows out_buf.to_numpy(np.float32, (out_size,)): out_size
//    is the ELEMENT count (131072), bytes are out_nbytes. My memset
//    covered out_size BYTES = first 8 of 32 rows; the rest stayed at the
//    harness's 0-fill and atomicMin(0,x)=0 pinned them to zero. Error
//    1.47 = max ref distance in the uncovered rows. R13's all-atomic
//    conversion was probably unnecessary but is kept (order-independent
//    by construction, ~65K extra atomics, negligible).
//  - Design unchanged (single compute dispatch, no reduce, no 16.8MB
//    partial round-trip): min commutes with sqrt; nonneg f32 bits are
//    uint-monotone -> blocks atomicMin final sqrt(max(best+s2,0)) into
//    out. Init 0x7F7F7F7F = 3.39e38 > any candidate. Padded tail q>=Lq:
//    pc==0 block atomicMin(0). Lp==0 rows: spare blocks atomicMin
//    sentinel sqrt(1e10) (q<Lq) / 0 (q>=Lq); spares exist exactly when
//    needed (each Lp==0 row frees its 32 units). Lq==0 rows: KACT==0,
//    pc0 zeroes all 4096, no scan. Every output element is covered.
//  - Main's scan identical to R9-R11. Query-skip KA in {4,8,12,16},
//    128-pt chunks, 2 v_pk_fma_f32 + v_min3_f32 per pair per query,
//    full f32 (absmax ~2e-3). No fences anywhere (R3 lesson).
//  - Pre-committed read (from R12): <=75us confirms the dispatch/
//    round-trip theory -> R15 attacks main's internals; >=81us -> null,
//    R15 rebuilds main's scan loop.

#define NQ 16
typedef float f2 __attribute__((ext_vector_type(2)));

template<int KA>
__device__ __forceinline__ void scan_queries(
    const float* __restrict__ Qrow,          // row base of query cloud
    const float4* __restrict__ sxy, const f2* __restrict__ sn,
    unsigned* __restrict__ orow_u, int tid)
{
    // KA*64 queries per wave; 4 state VGPRs per query (KA=16 -> ~90 total).
    float mx[KA], my[KA], s2[KA], best[KA];
    #pragma unroll
    for (int k = 0; k < KA; ++k) {
        const float2 q = ((const float2*)Qrow)[tid + k * 256];
        mx[k] = -2.f * q.x;
        my[k] = -2.f * q.y;
        s2[k] = fmaf(q.x, q.x, q.y * q.y);
        best[k] = 3.0e38f;
    }

    // Per point-pair per query: 2 v_pk_fma_f32 (scalar op_sel broadcast)
    // + 1 v_min3_f32; 2 broadcast LDS reads amortized over KA queries.
    #pragma unroll 4
    for (int j = 0; j < 64; ++j) {
        const float4 xy = sxy[j];
        const f2 xp = f2{xy.x, xy.y};
        const f2 yp = f2{xy.z, xy.w};
        const f2 np = sn[j];
        #pragma unroll
        for (int k = 0; k < KA; ++k) {
            f2 v = xp * mx[k] + np;       // pk_fma: n - 2qx*tx
            v = yp * my[k] + v;           // pk_fma: n - 2q.t
            best[k] = fminf(best[k], fminf(v.x, v.y));  // v_min3_f32
        }
    }

    // Final value per query from this block; global combine by atomicMin
    // on the uint bit pattern (monotone for nonneg floats). Fire-and-forget.
    #pragma unroll
    for (int k = 0; k < KA; ++k) {
        const float d = sqrtf(fmaxf(best[k] + s2[k], 0.f));
        atomicMin(orow_u + tid + k * 256, __float_as_uint(d));
    }
}

__global__ __launch_bounds__(256, 2) void chamfer_main(
    const float* __restrict__ src, const float* __restrict__ tgt,
    const int* __restrict__ slen, const int* __restrict__ tlen,
    float* __restrict__ out)
{
    __shared__ float4 sh_xy[64];   // {x0,x1,y0,y1} per point-pair
    __shared__ f2     sh_n[64];    // {|t0|^2, |t1|^2}

    const int g   = blockIdx.x;
    const int tid = threadIdx.x;

    // Compacted work lookup: g -> (row, pc). Uniform SALU.
    int row = -1, pc = 0, Lp = 0, acc = 0;
    #pragma unroll
    for (int rr = 0; rr < 32; ++rr) {
        const int L = (rr < 16) ? tlen[rr] : slen[rr - 16];  // search-side length
        const int n = (L + 127) >> 7;                        // active 128-pt chunks
        if (row < 0 && g < acc + n) { row = rr; pc = g - acc; Lp = L; }
        acc += n;
    }

    if (row < 0) {
        // Spare block: cleanup duty for rows with NO compute blocks
        // (Lp == 0): min over empty set = BIG -> sqrt(1e10) for q < Lq,
        // 0 for padded queries. Atomic-only (order-independent).
        const int cr = g - acc;                  // acc == total active units
        if (cr < 32) {
            const int dirc = cr >> 4, bc = cr & 15;
            const int Lpc = dirc ? slen[bc] : tlen[bc];
            if (Lpc == 0) {
                const int Lqc = dirc ? tlen[bc] : slen[bc];
                unsigned* op = (unsigned*)(out + cr * 4096);
                const unsigned sent = __float_as_uint(sqrtf(1e10f));
                #pragma unroll
                for (int k = 0; k < 16; ++k) {
                    const int q = tid + k * 256;
                    atomicMin(op + q, (q < Lqc) ? sent : 0u);
                }
            }
        }
        return;
    }
    const int dir = row >> 4, b = row & 15;

    const int Lq = dir ? tlen[b] : slen[b];      // query-side valid length
    unsigned* orow_u = (unsigned*)(out + row * 4096);

    // pc==0 forces the padded-query tail to 0 via atomicMin(0): any
    // interleaving with dead-value atomics ends at 0 (uint-min).
    if (pc == 0) {
        #pragma unroll
        for (int k = 0; k < 16; ++k) {
            const int q = tid + k * 256;
            if (q >= Lq) atomicMin(orow_u + q, 0u);
        }
    }

    const int KACT = (Lq + 255) >> 8;            // 0..16 active query slices
    if (KACT == 0) return;                       // uniform: no valid queries

    const float* Q = dir ? tgt : src;
    const float* P = dir ? src : tgt;

    // Stage 128 points (64 pairs), pair-packed; poison n for idx >= Lp.
    if (tid < 64) {
        const int base = pc * 128 + tid * 2;
        const float4 pp = ((const float4*)P)[(b * 4096 + base) >> 1];  // {x0,y0,x1,y1}
        const float n0 = (base + 0 < Lp) ? fmaf(pp.x, pp.x, pp.y * pp.y) : 1e30f;
        const float n1 = (base + 1 < Lp) ? fmaf(pp.z, pp.z, pp.w * pp.w) : 1e30f;
        sh_xy[tid] = make_float4(pp.x, pp.z, pp.y, pp.w);    // {x0,x1,y0,y1}
        sh_n[tid]  = f2{n0, n1};
    }
    __syncthreads();

    const float* Qrow = Q + b * 8192;            // row base (float2 elems)

    // Uniform dispatch on rounded-up active query slices. Queries in
    // [Lq, KA*256) get atomicMin'd with dead values but are forced to 0
    // by pc0's atomicMin(0) (order-independent).
    switch ((KACT + 3) >> 2) {
        case 1:  scan_queries< 4>(Qrow, sh_xy, sh_n, orow_u, tid); break;
        case 2:  scan_queries< 8>(Qrow, sh_xy, sh_n, orow_u, tid); break;
        case 3:  scan_queries<12>(Qrow, sh_xy, sh_n, orow_u, tid); break;
        default: scan_queries<16>(Qrow, sh_xy, sh_n, orow_u, tid); break;
    }
}

extern "C" void kernel_launch(void* const* d_in, const int* in_sizes, int n_in,
                              void* d_out, int out_size, void* d_ws, size_t ws_size,
                              hipStream_t stream) {
    const float* src = (const float*)d_in[0];   // [16,4096,2] f32
    const float* tgt = (const float*)d_in[1];   // [16,4096,2] f32
    const int* slen  = (const int*)d_in[2];     // [16] i32
    const int* tlen  = (const int*)d_in[3];     // [16] i32
    (void)d_ws; (void)ws_size;                  // workspace unused (no partials)

    // Init out to 0x7F7F7F7F = 3.39e38f (> any candidate). out_size is the
    // ELEMENT count (harness reads np.float32[(out_size,)]) -> bytes = x4.
    // 2*16*4096 elems = 131072 -> 524288 bytes.
    hipMemsetAsync(d_out, 0x7F, (size_t)out_size * sizeof(float), stream);
    chamfer_main<<<1024, 256, 0, stream>>>(src, tgt, slen, tlen, (float*)d_out);
}